// Round 4
// baseline (192.965 us; speedup 1.0000x reference)
//
#include <hip/hip_runtime.h>
#include <hip/hip_bf16.h>

// Problem constants (from reference)
#define E_   16
#define B_   4096
#define DX_  128
#define DC_  64
#define DIN_ 192
#define DH_  1024
#define DO_  128

// Tile config: one block = one expert x 256 rows; DH chunked by 64.
#define BM 256
#define KC 64
#define NCHUNK (DH_ / KC)   // 16
#define NT 512              // 8 waves

// LDS union layout (units: shorts). Total 73728 shorts = 144 KB.
// Prologue: front 49152 shorts ([256][192] XC scratch) — consumed before packs.
// Steady state: W1B[2] | W2B[2] | HB[2], all double-buffered.
#define W1B_OFF 0
#define W1B_STR 12288   // [64][192] bf16 = 24 KB each
#define W2B_OFF 24576
#define W2B_STR 8192    // [128][64] bf16 = 16 KB each
#define HB_OFF  40960
#define HB_STR  16384   // [256][64] bf16 = 32 KB each

typedef __attribute__((ext_vector_type(4))) float f32x4;
typedef __attribute__((ext_vector_type(8))) short bf16x8;

__device__ __forceinline__ unsigned f2bf_u(float f) {
    union { float f; unsigned u; } v; v.f = f;
    return (v.u + 0x7fffu + ((v.u >> 16) & 1u)) >> 16;   // RNE
}
__device__ __forceinline__ uint2 pack4(float4 v) {
    uint2 r;
    r.x = f2bf_u(v.x) | (f2bf_u(v.y) << 16);
    r.y = f2bf_u(v.z) | (f2bf_u(v.w) << 16);
    return r;
}
// Swizzled short-index: row r (row stride S shorts), byte-col cb.
// XOR byte-bits 4..6 with (r&7). Same formula on EVERY read and write
// (both-sides rule #21). Verified PASSED in round-2 kernel.
__device__ __forceinline__ int swz(int r, int S, int cb) {
    return r * S + ((cb ^ ((r & 7) << 4)) >> 1);
}

__global__ __launch_bounds__(NT, 2)
void moe_fused_kernel(const float* __restrict__ x, const float* __restrict__ cond,
                      const float* __restrict__ W1, const float* __restrict__ b1,
                      const float* __restrict__ W2, const float* __restrict__ b2,
                      float* __restrict__ out) {
    __shared__ short LDSU[73728];   // 144 KB

    // XCD swizzle: bid%8 = XCD; XCD x owns experts {2x,2x+1} -> per-XCD
    // fp32 weight working set 2.5 MB < 4 MB L2.
    const int bid = blockIdx.x;             // 0..255
    const int xcd = bid & 7;
    const int s   = bid >> 3;               // 0..31
    const int e   = 2 * xcd + (s & 1);
    const int row0 = (s >> 1) * BM;

    const int tid  = threadIdx.x;
    const int w    = tid >> 6;              // wave 0..7
    const int lane = tid & 63;
    const int lr   = lane & 15;
    const int lg   = lane >> 4;
    const int band = w * 32;                // G1: wave w owns rows band..band+31
    const int wr   = w >> 1, wc2 = w & 1;   // G2: 4x2 wave grid

    const float4* g1base = (const float4*)(W1 + (size_t)e * DH_ * DIN_);

    // ---- issue W1(0) loads first: they land during XC staging ----
    float4 r1[6];
#pragma unroll
    for (int i = 0; i < 6; ++i) r1[i] = g1base[tid + NT * i];

    // ---- stage XC = concat(x, cond) -> bf16 LDS scratch [256][192] ----
    {
        const float4* gx = (const float4*)(x + (size_t)(e * B_ + row0) * DX_);
#pragma unroll
        for (int i = 0; i < 16; ++i) {              // 8192 float4 of x
            int g = tid + NT * i;
            int r = g >> 5, c = g & 31;
            *(uint2*)&LDSU[swz(r, DIN_, c * 8)] = pack4(gx[g]);
        }
        const float4* gc = (const float4*)(cond + (size_t)(e * B_ + row0) * DC_);
#pragma unroll
        for (int i = 0; i < 8; ++i) {               // 4096 float4 of cond
            int g = tid + NT * i;
            int r = g >> 4, c = g & 15;
            *(uint2*)&LDSU[128 + swz(r, DIN_, c * 8)] = pack4(gc[g]);
        }
    }
    __syncthreads();    // XC scratch ready

    // ---- hoist XC A-fragments into registers (chunk-invariant): 48 VGPR ----
    bf16x8 xcreg[2][6];
#pragma unroll
    for (int mf = 0; mf < 2; ++mf)
#pragma unroll
        for (int kk = 0; kk < 6; ++kk)
            xcreg[mf][kk] = *(const bf16x8*)&LDSU[swz(band + mf * 16 + lr, DIN_, kk * 64 + lg * 16)];
    __syncthreads();    // all waves done with scratch; packs may overwrite

    // ---- prologue: pack W1(0) -> W1B[0]; preload r1=W1(1), r2=W2(0) ----
#pragma unroll
    for (int i = 0; i < 6; ++i) {
        int g = tid + NT * i;
        int r = g / 48, cc = g - r * 48;            // 48 float4 per 192-col row
        *(uint2*)&LDSU[W1B_OFF + swz(r, DIN_, cc * 8)] = pack4(r1[i]);
    }
#pragma unroll
    for (int i = 0; i < 6; ++i)
        r1[i] = g1base[(KC * DIN_ / 4) + tid + NT * i];     // W1(1)
    float4 r2[4];
    {
        const float* g2 = W2 + (size_t)e * DO_ * DH_;       // W2(0)
#pragma unroll
        for (int i = 0; i < 4; ++i) {
            int g = tid + NT * i;
            int r = g >> 4, cc = g & 15;
            r2[i] = *(const float4*)(g2 + (size_t)r * DH_ + cc * 4);
        }
    }
    __syncthreads();    // W1B[0] visible

    f32x4 acc2[4][4] = {};   // y accumulator (64 VGPR), persists across chunks

    // Steady state, ONE barrier per chunk. Parity invariants at entry to body c:
    //   W1B[c&1]     = W1(c)        (packed in body c-1 / prologue)
    //   r1           = W1(c+1)      (issued in body c-1 / prologue)
    //   r2           = W2(c)        (issued in body c-1 / prologue)
    //   HB[(c-1)&1]  = relu-h(c-1)  (written by G1 in body c-1)
    //   W2B[(c-1)&1] = W2(c-1)      (packed in body c-1)
    for (int c = 0; c < NCHUNK; ++c) {
        const int pc = c & 1, pp = pc ^ 1;

        // b1 fragment for G1(c) — tiny, hidden under G2
        float b1v[4];
#pragma unroll
        for (int nf = 0; nf < 4; ++nf)
            b1v[nf] = b1[e * DH_ + c * KC + nf * 16 + lr];

        // (1) pack W2(c) -> W2B[pc]  (parity != G2's reads below)
#pragma unroll
        for (int i = 0; i < 4; ++i) {
            int g = tid + NT * i;
            int r = g >> 4, cc = g & 15;
            *(uint2*)&LDSU[W2B_OFF + pc * W2B_STR + swz(r, KC, cc * 8)] = pack4(r2[i]);
        }
        // (2) pack W1(c+1) -> W1B[pp]  (parity != G1's reads below)
        if (c + 1 < NCHUNK) {
#pragma unroll
            for (int i = 0; i < 6; ++i) {
                int g = tid + NT * i;
                int r = g / 48, cc = g - r * 48;
                *(uint2*)&LDSU[W1B_OFF + pp * W1B_STR + swz(r, DIN_, cc * 8)] = pack4(r1[i]);
            }
        }
        // (3) issue next loads; land under ~80 MFMA below, cheap drain at barrier
        if (c + 2 < NCHUNK) {
#pragma unroll
            for (int i = 0; i < 6; ++i)
                r1[i] = g1base[(c + 2) * (KC * DIN_ / 4) + tid + NT * i];
        }
        if (c + 1 < NCHUNK) {
            const float* g2 = W2 + (size_t)e * DO_ * DH_ + (size_t)(c + 1) * KC;
#pragma unroll
            for (int i = 0; i < 4; ++i) {
                int g = tid + NT * i;
                int r = g >> 4, cc = g & 15;
                r2[i] = *(const float4*)(g2 + (size_t)r * DH_ + cc * 4);
            }
        }

        // (4) G2(c-1): y += relu_h(c-1) @ W2(c-1)^T   [reads parity pp bufs]
        if (c > 0) {
#pragma unroll
            for (int kk = 0; kk < KC / 32; ++kk) {
                bf16x8 af[4], bfr[4];
#pragma unroll
                for (int mf = 0; mf < 4; ++mf) {
                    int r = wr * 64 + mf * 16 + lr;
                    af[mf] = *(const bf16x8*)&LDSU[HB_OFF + pp * HB_STR + swz(r, KC, kk * 64 + lg * 16)];
                }
#pragma unroll
                for (int nf = 0; nf < 4; ++nf) {
                    int r = wc2 * 64 + nf * 16 + lr;
                    bfr[nf] = *(const bf16x8*)&LDSU[W2B_OFF + pp * W2B_STR + swz(r, KC, kk * 64 + lg * 16)];
                }
#pragma unroll
                for (int mf = 0; mf < 4; ++mf)
#pragma unroll
                    for (int nf = 0; nf < 4; ++nf)
                        acc2[mf][nf] = __builtin_amdgcn_mfma_f32_16x16x32_bf16(af[mf], bfr[nf], acc2[mf][nf], 0, 0, 0);
            }
        }

        // (5) G1(c): h(c) = XC @ W1(c)^T  [reads W1B[pc]; A from registers]
        f32x4 acc1[2][4] = {};
#pragma unroll
        for (int kk = 0; kk < DIN_ / 32; ++kk) {    // 6 k-steps
            bf16x8 bfr[4];
#pragma unroll
            for (int nf = 0; nf < 4; ++nf) {
                int r = nf * 16 + lr;
                bfr[nf] = *(const bf16x8*)&LDSU[W1B_OFF + pc * W1B_STR + swz(r, DIN_, kk * 64 + lg * 16)];
            }
#pragma unroll
            for (int mf = 0; mf < 2; ++mf)
#pragma unroll
                for (int nf = 0; nf < 4; ++nf)
                    acc1[mf][nf] = __builtin_amdgcn_mfma_f32_16x16x32_bf16(xcreg[mf][kk], bfr[nf], acc1[mf][nf], 0, 0, 0);
        }
        // epilogue1: relu(acc1+b1) -> HB[pc].  D layout (m89): row=lg*4+j, col=lr
#pragma unroll
        for (int mf = 0; mf < 2; ++mf)
#pragma unroll
            for (int nf = 0; nf < 4; ++nf)
#pragma unroll
                for (int j = 0; j < 4; ++j) {
                    float v = fmaxf(acc1[mf][nf][j] + b1v[nf], 0.f);
                    int hr = band + mf * 16 + lg * 4 + j;
                    int hc = nf * 16 + lr;
                    LDSU[HB_OFF + pc * HB_STR + swz(hr, KC, 2 * hc)] = (short)f2bf_u(v);
                }

        __syncthreads();   // the ONE barrier: flips all parities
    }

    // ---- drain: G2(NCHUNK-1), reads parity (NCHUNK-1)&1 = 1 ----
    {
        const int pl = (NCHUNK - 1) & 1;
#pragma unroll
        for (int kk = 0; kk < KC / 32; ++kk) {
            bf16x8 af[4], bfr[4];
#pragma unroll
            for (int mf = 0; mf < 4; ++mf) {
                int r = wr * 64 + mf * 16 + lr;
                af[mf] = *(const bf16x8*)&LDSU[HB_OFF + pl * HB_STR + swz(r, KC, kk * 64 + lg * 16)];
            }
#pragma unroll
            for (int nf = 0; nf < 4; ++nf) {
                int r = wc2 * 64 + nf * 16 + lr;
                bfr[nf] = *(const bf16x8*)&LDSU[W2B_OFF + pl * W2B_STR + swz(r, KC, kk * 64 + lg * 16)];
            }
#pragma unroll
            for (int mf = 0; mf < 4; ++mf)
#pragma unroll
                for (int nf = 0; nf < 4; ++nf)
                    acc2[mf][nf] = __builtin_amdgcn_mfma_f32_16x16x32_bf16(af[mf], bfr[nf], acc2[mf][nf], 0, 0, 0);
        }
    }

    // ---- final epilogue: y = acc2 + b2 (fp32 out) ----
    float b2v[4];
#pragma unroll
    for (int nf = 0; nf < 4; ++nf)
        b2v[nf] = b2[e * DO_ + wc2 * 64 + nf * 16 + lr];
#pragma unroll
    for (int mf = 0; mf < 4; ++mf)
#pragma unroll
        for (int nf = 0; nf < 4; ++nf)
#pragma unroll
            for (int j = 0; j < 4; ++j) {
                int m = wr * 64 + mf * 16 + lg * 4 + j;
                int o = wc2 * 64 + nf * 16 + lr;
                out[(size_t)(e * B_ + row0 + m) * DO_ + o] = acc2[mf][nf][j] + b2v[nf];
            }
}

extern "C" void kernel_launch(void* const* d_in, const int* in_sizes, int n_in,
                              void* d_out, int out_size, void* d_ws, size_t ws_size,
                              hipStream_t stream) {
    const float* x    = (const float*)d_in[0];
    const float* cond = (const float*)d_in[1];
    const float* W1   = (const float*)d_in[2];
    const float* b1   = (const float*)d_in[3];
    const float* W2   = (const float*)d_in[4];
    const float* b2   = (const float*)d_in[5];
    float* out = (float*)d_out;

    dim3 grid(E_ * (B_ / BM));   // 256 blocks = 1 per CU
    dim3 block(NT);              // 512 threads = 8 waves
    moe_fused_kernel<<<grid, block, 0, stream>>>(x, cond, W1, b1, W2, b2, out);
}

// Round 6
// 170.905 us; speedup vs baseline: 1.1291x; 1.1291x over previous
//
#include <hip/hip_runtime.h>
#include <hip/hip_bf16.h>

// Problem constants (from reference)
#define E_   16
#define B_   4096
#define DX_  128
#define DC_  64
#define DIN_ 192
#define DH_  1024
#define DO_  128

// Tile config: one block = one expert x 256 rows; DH chunked by 64.
#define BM 256
#define KC 64
#define NCHUNK (DH_ / KC)   // 16
#define NT 1024             // 16 waves = 4 waves/SIMD

// LDS union layout (units: shorts). Total 73728 shorts = 144 KB.
// Prologue: front 49152 shorts ([256][192] XC scratch) — consumed into regs
// before the packs overwrite it. Steady: W1B[2] | W2B[2] | HB[2] dbuf.
#define W1B_OFF 0
#define W1B_STR 12288   // [64][192] bf16 = 24 KB each
#define W2B_OFF 24576
#define W2B_STR 8192    // [128][64] bf16 = 16 KB each
#define HB_OFF  40960
#define HB_STR  16384   // [256][64] bf16 = 32 KB each

#define NW1U2 (E_ * DH_ * DIN_ / 4)   // 786432 uint2 of bf16 W1 in ws
#define NW2U2 (E_ * DO_ * DH_ / 4)    // 524288 uint2 of bf16 W2 in ws
#define WS_BYTES ((size_t)(NW1U2 + NW2U2) * 8)   // 10.5 MB

typedef __attribute__((ext_vector_type(4))) float f32x4;
typedef __attribute__((ext_vector_type(8))) short bf16x8;

__device__ __forceinline__ unsigned f2bf_u(float f) {
    union { float f; unsigned u; } v; v.f = f;
    return (v.u + 0x7fffu + ((v.u >> 16) & 1u)) >> 16;   // RNE
}
__device__ __forceinline__ uint2 pack4(float4 v) {
    uint2 r;
    r.x = f2bf_u(v.x) | (f2bf_u(v.y) << 16);
    r.y = f2bf_u(v.z) | (f2bf_u(v.w) << 16);
    return r;
}
// Swizzled short-index: row r (stride S shorts), byte-col cb. XOR byte bits
// 4..6 with (r&7). Same formula on every read and write (rule #21).
// Proven PASSED in rounds 2-3.
__device__ __forceinline__ int swz(int r, int S, int cb) {
    return r * S + ((cb ^ ((r & 7) << 4)) >> 1);
}

// ---- pre-pass: W1,W2 fp32 -> bf16 into ws (grid-stride, memory-bound) ----
__global__ __launch_bounds__(256)
void convert_w(const float4* __restrict__ W1, const float4* __restrict__ W2,
               uint2* __restrict__ ws) {
    const int ntot = NW1U2 + NW2U2;
    for (int i = blockIdx.x * 256 + threadIdx.x; i < ntot; i += gridDim.x * 256) {
        float4 v = (i < NW1U2) ? W1[i] : W2[i - NW1U2];
        ws[i] = pack4(v);
    }
}

template <bool WS>
__global__ __launch_bounds__(NT, 4)
void moe_fused_kernel(const float* __restrict__ x, const float* __restrict__ cond,
                      const float* __restrict__ W1, const float* __restrict__ b1,
                      const float* __restrict__ W2, const float* __restrict__ b2,
                      const uint2* __restrict__ wsw, float* __restrict__ out) {
    __shared__ short LDSU[73728];   // 144 KB -> 1 block/CU, 16 waves = 4/SIMD

    // XCD swizzle: bid%8 = XCD; XCD k owns experts {2k,2k+1} -> per-XCD bf16
    // weight set 1.3 MB < 4 MB L2.
    const int bid = blockIdx.x;             // 0..255
    const int xcd = bid & 7;
    const int s   = bid >> 3;               // 0..31
    const int e   = 2 * xcd + (s & 1);
    const int row0 = (s >> 1) * BM;

    const int tid  = threadIdx.x;
    const int w    = tid >> 6;              // wave 0..15
    const int lane = tid & 63;
    const int lr   = lane & 15;
    const int lg   = lane >> 4;
    const int wr   = w >> 2, wc2 = w & 3;   // G2: 4x4 wave grid (64r x 32c tiles)

    const uint2*  ws1 = wsw + (size_t)e * (DH_ * DIN_ / 4);            // bf16 W1[e]
    const uint2*  ws2 = wsw + NW1U2 + (size_t)e * (DO_ * DH_ / 4);     // bf16 W2[e]
    const float4* g1f = (const float4*)(W1 + (size_t)e * DH_ * DIN_);  // fp32 fallback
    const float*  g2f = W2 + (size_t)e * DO_ * DH_;

    uint2 r1[3]; float4 r1f[3];   // W1 chunk staging (one set DCE'd per instantiation)
    uint2 r2[2]; float4 r2f[2];   // W2 chunk staging

    // ---- issue W1(0) loads first: land during XC staging ----
    if constexpr (WS) {
#pragma unroll
        for (int i = 0; i < 3; ++i) r1[i] = ws1[tid + NT * i];
    } else {
#pragma unroll
        for (int i = 0; i < 3; ++i) r1f[i] = g1f[tid + NT * i];
    }

    // ---- stage XC = concat(x, cond) -> bf16 LDS scratch [256][192] ----
    {
        const float4* gx = (const float4*)(x + (size_t)(e * B_ + row0) * DX_);
#pragma unroll
        for (int i = 0; i < 8; ++i) {               // 8192 float4 of x
            int g = tid + NT * i;
            int r = g >> 5, c = g & 31;
            *(uint2*)&LDSU[swz(r, DIN_, c * 8)] = pack4(gx[g]);
        }
        const float4* gc = (const float4*)(cond + (size_t)(e * B_ + row0) * DC_);
#pragma unroll
        for (int i = 0; i < 4; ++i) {               // 4096 float4 of cond
            int g = tid + NT * i;
            int r = g >> 4, c = g & 15;
            *(uint2*)&LDSU[128 + swz(r, DIN_, c * 8)] = pack4(gc[g]);
        }
    }
    __syncthreads();    // XC scratch ready

    // ---- hoist XC A-fragments (chunk-invariant) into 24 VGPR ----
    // G1: wave w owns rows w*16 .. w*16+15
    bf16x8 xcreg[6];
#pragma unroll
    for (int kk = 0; kk < 6; ++kk)
        xcreg[kk] = *(const bf16x8*)&LDSU[swz(w * 16 + lr, DIN_, kk * 64 + lg * 16)];
    __syncthreads();    // scratch consumed; packs may overwrite

    // ---- prologue: pack W1(0) -> W1B[0]; preload r1=W1(1), r2=W2(0) ----
#pragma unroll
    for (int i = 0; i < 3; ++i) {
        int g = tid + NT * i;
        int r = g / 48, cc = g - r * 48;            // 48 x 16B-units per 192-col row
        uint2 pv; if constexpr (WS) pv = r1[i]; else pv = pack4(r1f[i]);
        *(uint2*)&LDSU[W1B_OFF + swz(r, DIN_, cc * 8)] = pv;
    }
    if constexpr (WS) {
#pragma unroll
        for (int i = 0; i < 3; ++i) r1[i] = ws1[3072 + tid + NT * i];       // W1(1)
#pragma unroll
        for (int i = 0; i < 2; ++i) {                                        // W2(0)
            int g = tid + NT * i;
            int r = g >> 4, cc = g & 15;
            r2[i] = ws2[r * 256 + cc];
        }
    } else {
#pragma unroll
        for (int i = 0; i < 3; ++i) r1f[i] = g1f[3072 + tid + NT * i];
#pragma unroll
        for (int i = 0; i < 2; ++i) {
            int g = tid + NT * i;
            int r = g >> 4, cc = g & 15;
            r2f[i] = *(const float4*)(g2f + (size_t)r * DH_ + cc * 4);
        }
    }
    __syncthreads();    // W1B[0] visible

    f32x4 acc2[4][2] = {};   // y accumulator: 32 VGPR, persists across chunks

    // ONE barrier per chunk. Invariants at entry to body c (proven round 3):
    //   W1B[c&1] = W1(c); r1 = W1(c+1); r2 = W2(c);
    //   HB[(c-1)&1] = relu-h(c-1); W2B[(c-1)&1] = W2(c-1)
    for (int c = 0; c < NCHUNK; ++c) {
        const int pc = c & 1, pp = pc ^ 1;

        float b1v[4];
#pragma unroll
        for (int nf = 0; nf < 4; ++nf)
            b1v[nf] = b1[e * DH_ + c * KC + nf * 16 + lr];

        // (1) pack W2(c) -> W2B[pc]
#pragma unroll
        for (int i = 0; i < 2; ++i) {
            int g = tid + NT * i;
            int r = g >> 4, cc = g & 15;
            uint2 pv; if constexpr (WS) pv = r2[i]; else pv = pack4(r2f[i]);
            *(uint2*)&LDSU[W2B_OFF + pc * W2B_STR + swz(r, KC, cc * 8)] = pv;
        }
        // (2) pack W1(c+1) -> W1B[pp]
        if (c + 1 < NCHUNK) {
#pragma unroll
            for (int i = 0; i < 3; ++i) {
                int g = tid + NT * i;
                int r = g / 48, cc = g - r * 48;
                uint2 pv; if constexpr (WS) pv = r1[i]; else pv = pack4(r1f[i]);
                *(uint2*)&LDSU[W1B_OFF + pp * W1B_STR + swz(r, DIN_, cc * 8)] = pv;
            }
        }
        // (3) issue next loads; land under the ~40 MFMA below
        if (c + 2 < NCHUNK) {
            if constexpr (WS) {
#pragma unroll
                for (int i = 0; i < 3; ++i) r1[i] = ws1[(c + 2) * 3072 + tid + NT * i];
            } else {
#pragma unroll
                for (int i = 0; i < 3; ++i) r1f[i] = g1f[(c + 2) * 3072 + tid + NT * i];
            }
        }
        if (c + 1 < NCHUNK) {
            if constexpr (WS) {
#pragma unroll
                for (int i = 0; i < 2; ++i) {
                    int g = tid + NT * i;
                    int r = g >> 4, cc = g & 15;
                    r2[i] = ws2[r * 256 + (c + 1) * 16 + cc];
                }
            } else {
#pragma unroll
                for (int i = 0; i < 2; ++i) {
                    int g = tid + NT * i;
                    int r = g >> 4, cc = g & 15;
                    r2f[i] = *(const float4*)(g2f + (size_t)r * DH_ + (c + 1) * KC + cc * 4);
                }
            }
        }

        // (4) G2(c-1): y += relu_h(c-1) @ W2(c-1)^T  [parity pp]
        if (c > 0) {
#pragma unroll
            for (int kk = 0; kk < KC / 32; ++kk) {
                bf16x8 af[4], bfr[2];
#pragma unroll
                for (int mf = 0; mf < 4; ++mf)
                    af[mf] = *(const bf16x8*)&LDSU[HB_OFF + pp * HB_STR + swz(wr * 64 + mf * 16 + lr, KC, kk * 64 + lg * 16)];
#pragma unroll
                for (int nf = 0; nf < 2; ++nf)
                    bfr[nf] = *(const bf16x8*)&LDSU[W2B_OFF + pp * W2B_STR + swz(wc2 * 32 + nf * 16 + lr, KC, kk * 64 + lg * 16)];
#pragma unroll
                for (int mf = 0; mf < 4; ++mf)
#pragma unroll
                    for (int nf = 0; nf < 2; ++nf)
                        acc2[mf][nf] = __builtin_amdgcn_mfma_f32_16x16x32_bf16(af[mf], bfr[nf], acc2[mf][nf], 0, 0, 0);
            }
        }

        // (5) G1(c): h(c) rows w*16..+15 = XC @ W1(c)^T  [W1B[pc]; A in regs]
        f32x4 acc1[4] = {};
#pragma unroll
        for (int kk = 0; kk < DIN_ / 32; ++kk) {    // 6 k-steps
            bf16x8 bfr[4];
#pragma unroll
            for (int nf = 0; nf < 4; ++nf)
                bfr[nf] = *(const bf16x8*)&LDSU[W1B_OFF + pc * W1B_STR + swz(nf * 16 + lr, DIN_, kk * 64 + lg * 16)];
#pragma unroll
            for (int nf = 0; nf < 4; ++nf)
                acc1[nf] = __builtin_amdgcn_mfma_f32_16x16x32_bf16(xcreg[kk], bfr[nf], acc1[nf], 0, 0, 0);
        }
        // epilogue1: relu(acc1+b1) -> HB[pc].  D layout (m89): row=lg*4+j, col=lr
#pragma unroll
        for (int nf = 0; nf < 4; ++nf)
#pragma unroll
            for (int j = 0; j < 4; ++j) {
                float v = fmaxf(acc1[nf][j] + b1v[nf], 0.f);
                int hr = w * 16 + lg * 4 + j;
                int hc = nf * 16 + lr;
                LDSU[HB_OFF + pc * HB_STR + swz(hr, KC, 2 * hc)] = (short)f2bf_u(v);
            }

        __syncthreads();   // the ONE barrier: flips all parities
    }

    // ---- drain: G2(NCHUNK-1) at parity 1 ----
    {
        const int pl = (NCHUNK - 1) & 1;
#pragma unroll
        for (int kk = 0; kk < KC / 32; ++kk) {
            bf16x8 af[4], bfr[2];
#pragma unroll
            for (int mf = 0; mf < 4; ++mf)
                af[mf] = *(const bf16x8*)&LDSU[HB_OFF + pl * HB_STR + swz(wr * 64 + mf * 16 + lr, KC, kk * 64 + lg * 16)];
#pragma unroll
            for (int nf = 0; nf < 2; ++nf)
                bfr[nf] = *(const bf16x8*)&LDSU[W2B_OFF + pl * W2B_STR + swz(wc2 * 32 + nf * 16 + lr, KC, kk * 64 + lg * 16)];
#pragma unroll
            for (int mf = 0; mf < 4; ++mf)
#pragma unroll
                for (int nf = 0; nf < 2; ++nf)
                    acc2[mf][nf] = __builtin_amdgcn_mfma_f32_16x16x32_bf16(af[mf], bfr[nf], acc2[mf][nf], 0, 0, 0);
        }
    }

    // ---- final epilogue: y = acc2 + b2 (fp32 out) ----
    float b2v[2];
#pragma unroll
    for (int nf = 0; nf < 2; ++nf)
        b2v[nf] = b2[e * DO_ + wc2 * 32 + nf * 16 + lr];
#pragma unroll
    for (int mf = 0; mf < 4; ++mf)
#pragma unroll
        for (int nf = 0; nf < 2; ++nf)
#pragma unroll
            for (int j = 0; j < 4; ++j) {
                int m = wr * 64 + mf * 16 + lg * 4 + j;
                int o = wc2 * 32 + nf * 16 + lr;
                out[(size_t)(e * B_ + row0 + m) * DO_ + o] = acc2[mf][nf][j] + b2v[nf];
            }
}

extern "C" void kernel_launch(void* const* d_in, const int* in_sizes, int n_in,
                              void* d_out, int out_size, void* d_ws, size_t ws_size,
                              hipStream_t stream) {
    const float* x    = (const float*)d_in[0];
    const float* cond = (const float*)d_in[1];
    const float* W1   = (const float*)d_in[2];
    const float* b1   = (const float*)d_in[3];
    const float* W2   = (const float*)d_in[4];
    const float* b2   = (const float*)d_in[5];
    float* out = (float*)d_out;

    dim3 grid(E_ * (B_ / BM));   // 256 blocks = 1 per CU
    dim3 block(NT);              // 1024 threads = 16 waves

    const bool usews = (ws_size >= WS_BYTES) && (d_ws != nullptr);
    if (usews) {
        convert_w<<<2560, 256, 0, stream>>>((const float4*)W1, (const float4*)W2,
                                            (uint2*)d_ws);
        moe_fused_kernel<true><<<grid, block, 0, stream>>>(
            x, cond, W1, b1, W2, b2, (const uint2*)d_ws, out);
    } else {
        moe_fused_kernel<false><<<grid, block, 0, stream>>>(
            x, cond, W1, b1, W2, b2, (const uint2*)nullptr, out);
    }
}

// Round 7
// 155.330 us; speedup vs baseline: 1.2423x; 1.1003x over previous
//
#include <hip/hip_runtime.h>
#include <hip/hip_bf16.h>

// Problem constants
#define E_   16
#define B_   4096
#define DX_  128
#define DC_  64
#define DIN_ 192
#define DH_  1024
#define DO_  128

#define BM 256
#define KC 64
#define NCHUNK 16
#define NT 1024             // 16 waves = 4 waves/SIMD, VGPR cap 128

// LDS (shorts): W1B[2] | W2B[2] | HB[2] = 144 KB
#define W1B_OFF 0
#define W1B_STR 12288   // [64][192] bf16, swizzled image (24 KB)
#define W2B_OFF 24576
#define W2B_STR 8192    // [128][64] bf16, swizzled (16 KB)
#define HB_OFF  40960
#define HB_STR  16384   // [256][64] bf16, swizzled (32 KB)

#define NW1U2 (E_ * DH_ * DIN_ / 4)   // 786432 8B-units of bf16 W1
#define NW2U2 (E_ * DO_ * DH_ / 4)    // 524288 8B-units of bf16 W2
#define WS_BYTES ((size_t)(NW1U2 + NW2U2) * 8)   // 10.5 MB

typedef __attribute__((ext_vector_type(4))) float f32x4;
typedef __attribute__((ext_vector_type(8))) short bf16x8;

__device__ __forceinline__ unsigned f2bf_u(float f) {
    union { float f; unsigned u; } v; v.f = f;
    return (v.u + 0x7fffu + ((v.u >> 16) & 1u)) >> 16;   // RNE
}
__device__ __forceinline__ uint2 pack4(float4 v) {
    uint2 r;
    r.x = f2bf_u(v.x) | (f2bf_u(v.y) << 16);
    r.y = f2bf_u(v.z) | (f2bf_u(v.w) << 16);
    return r;
}
// XOR-swizzle (proven rounds 2-6, 0 conflicts): byte bits 4..6 ^= (row&7).
// Same formula on every producer and consumer of each buffer (rule #21).
__device__ __forceinline__ int swz(int r, int S, int cb) {
    return r * S + ((cb ^ ((r & 7) << 4)) >> 1);
}
__device__ __forceinline__ bf16x8 load8cvt(const float* p) {
    float4 a = *(const float4*)p;
    float4 b = *(const float4*)(p + 4);
    bf16x8 r;
    r[0] = (short)f2bf_u(a.x); r[1] = (short)f2bf_u(a.y);
    r[2] = (short)f2bf_u(a.z); r[3] = (short)f2bf_u(a.w);
    r[4] = (short)f2bf_u(b.x); r[5] = (short)f2bf_u(b.y);
    r[6] = (short)f2bf_u(b.z); r[7] = (short)f2bf_u(b.w);
    return r;
}
// async global->LDS, 16 B per lane; LDS dest = wave-uniform base + lane*16
__device__ __forceinline__ void gld_lds16(const void* g, void* l) {
    __builtin_amdgcn_global_load_lds(
        (const __attribute__((address_space(1))) unsigned int*)g,
        (__attribute__((address_space(3))) unsigned int*)l, 16, 0, 0);
}

// ---- pre-pass: W1 -> bf16 PRE-SWIZZLED per-chunk tiles; W2 -> bf16 linear ----
// ws1 block (e,chunk): 12288 shorts holding the swizzled [64][192] image, so a
// LINEAR global_load_lds deposit reproduces exactly what swz-reads expect.
__global__ __launch_bounds__(256)
void convert_w(const float4* __restrict__ W1, const float4* __restrict__ W2,
               uint2* __restrict__ ws) {
    const int ntot = NW1U2 + NW2U2;
    for (int i = blockIdx.x * 256 + threadIdx.x; i < ntot; i += gridDim.x * 256) {
        if (i < NW1U2) {
            float4 v = W1[i];
            int e  = i / (DH_ * 48);              // 48 8B-units per 192-col row
            int rr = i - e * (DH_ * 48);
            int hr = rr / 48, cu = rr - hr * 48;  // global h-row, unit-col
            int ch = hr >> 6, r = hr & 63;
            int S  = swz(r, DIN_, cu * 8);        // short idx, multiple of 4
            ws[(size_t)(e * 16 + ch) * 3072 + (S >> 2)] = pack4(v);
        } else {
            ws[i] = pack4(W2[i - NW1U2]);         // plain linear bf16 W2
        }
    }
}

template <bool WS>
__global__ __launch_bounds__(NT, 4)
void moe_fused_kernel(const float* __restrict__ x, const float* __restrict__ cond,
                      const float* __restrict__ W1, const float* __restrict__ b1,
                      const float* __restrict__ W2, const float* __restrict__ b2,
                      const uint2* __restrict__ wsw, float* __restrict__ out) {
    __shared__ short LDSU[73728];   // 144 KB -> 1 block/CU

    // XCD swizzle: XCD k owns experts {2k,2k+1}; per-XCD bf16 weights 1.3 MB < L2
    const int bid = blockIdx.x;             // 0..255
    const int xcd = bid & 7;
    const int s   = bid >> 3;
    const int e   = 2 * xcd + (s & 1);
    const int row0 = (s >> 1) * BM;

    const int tid  = threadIdx.x;
    const int w    = tid >> 6;              // wave 0..15
    const int lane = tid & 63;
    const int lr   = lane & 15;
    const int lg   = lane >> 4;
    const int wo   = w & 1;                 // G2: o-band of 64
    const int wm   = w >> 1;                // G2: m-band of 32

    const char*  ws1b = (const char*)wsw;   // swizzled bf16 W1 tiles
    const uint2* ws2  = wsw + NW1U2 + (size_t)e * (DO_ * DH_ / 4);
    const float4* g1f = (const float4*)(W1 + (size_t)e * DH_ * DIN_);  // fallback
    const float*  g2f = W2 + (size_t)e * DO_ * DH_;

    // ---- xcreg: this wave's 16 XC rows (row w*16+lr), direct global->reg ----
    bf16x8 xcreg[6];
    {
        const float* xrow = x    + (size_t)(e * B_ + row0 + w * 16 + lr) * DX_;
        const float* crow = cond + (size_t)(e * B_ + row0 + w * 16 + lr) * DC_;
#pragma unroll
        for (int kk = 0; kk < 4; ++kk) xcreg[kk] = load8cvt(xrow + kk * 32 + lg * 8);
#pragma unroll
        for (int kk = 4; kk < 6; ++kk) xcreg[kk] = load8cvt(crow + (kk - 4) * 32 + lg * 8);
    }

    // ---- prologue: stage W1(0) -> W1B[0]; preload r2 = W2(0) ----
    uint2  r2[2]; float4 r2f[2]; float4 r1f[3];
    if constexpr (WS) {
        for (int q = w; q < 24; q += 16)   // 24 x 1KB DMA calls, <=2 per wave
            gld_lds16(ws1b + (size_t)(e * 16 + 0) * 24576 + q * 1024 + lane * 16,
                      (char*)&LDSU[W1B_OFF] + q * 1024);
#pragma unroll
        for (int i = 0; i < 2; ++i) {
            int g = tid + NT * i, r = g >> 4, cc = g & 15;
            r2[i] = ws2[r * 256 + cc];
        }
    } else {
#pragma unroll
        for (int i = 0; i < 3; ++i) r1f[i] = g1f[tid + NT * i];   // W1(0)
#pragma unroll
        for (int i = 0; i < 3; ++i) {
            int g = tid + NT * i, r = g / 48, cu = g - r * 48;
            *(uint2*)&LDSU[W1B_OFF + swz(r, DIN_, cu * 8)] = pack4(r1f[i]);
        }
#pragma unroll
        for (int i = 0; i < 3; ++i) r1f[i] = g1f[3072 + tid + NT * i];   // W1(1)
#pragma unroll
        for (int i = 0; i < 2; ++i) {
            int g = tid + NT * i, r = g >> 4, cc = g & 15;
            r2f[i] = *(const float4*)(g2f + (size_t)r * DH_ + cc * 4);
        }
    }
    __syncthreads();    // W1B[0] ready (drains DMA)

    f32x4 acc2[4][2] = {};   // D[o][m]: of 0..3, nf 0..1 -> 32 VGPR

    // ONE barrier/chunk. Entry invariants: W1B[c&1]=W1(c); r2=W2(c);
    // HB[(c-1)&1]=relu-h(c-1); W2B[(c-1)&1]=W2(c-1).
    for (int c = 0; c < NCHUNK; ++c) {
        const int pc = c & 1, pp = pc ^ 1;

        // (1) pack W2(c) -> W2B[pc]
#pragma unroll
        for (int i = 0; i < 2; ++i) {
            int g = tid + NT * i, r = g >> 4, cc = g & 15;
            uint2 pv; if constexpr (WS) pv = r2[i]; else pv = pack4(r2f[i]);
            *(uint2*)&LDSU[W2B_OFF + pc * W2B_STR + swz(r, KC, cc * 8)] = pv;
        }
        // (2) stage W1(c+1) -> W1B[pp]: DMA (WS) or pack+reload (fallback)
        if (c + 1 < NCHUNK) {
            if constexpr (WS) {
                for (int q = w; q < 24; q += 16)
                    gld_lds16(ws1b + (size_t)(e * 16 + c + 1) * 24576 + q * 1024 + lane * 16,
                              (char*)&LDSU[W1B_OFF + pp * W1B_STR] + q * 1024);
            } else {
#pragma unroll
                for (int i = 0; i < 3; ++i) {
                    int g = tid + NT * i, r = g / 48, cu = g - r * 48;
                    *(uint2*)&LDSU[W1B_OFF + pp * W1B_STR + swz(r, DIN_, cu * 8)] = pack4(r1f[i]);
                }
                if (c + 2 < NCHUNK) {
#pragma unroll
                    for (int i = 0; i < 3; ++i) r1f[i] = g1f[(c + 2) * 3072 + tid + NT * i];
                }
            }
        }
        // (3) issue r2 = W2(c+1) (lands under G2+G1)
        if (c + 1 < NCHUNK) {
            if constexpr (WS) {
#pragma unroll
                for (int i = 0; i < 2; ++i) {
                    int g = tid + NT * i, r = g >> 4, cc = g & 15;
                    r2[i] = ws2[r * 256 + (c + 1) * 16 + cc];
                }
            } else {
#pragma unroll
                for (int i = 0; i < 2; ++i) {
                    int g = tid + NT * i, r = g >> 4, cc = g & 15;
                    r2f[i] = *(const float4*)(g2f + (size_t)r * DH_ + (c + 1) * KC + cc * 4);
                }
            }
        }

        // (4) G2(c-1): acc2[o][m] += W2(c-1)[o,k] * H(c-1)[m,k]  [parity pp]
        if (c > 0) {
#pragma unroll
            for (int kk = 0; kk < 2; ++kk) {
                bf16x8 aW2[4], bH[2];
#pragma unroll
                for (int of = 0; of < 4; ++of)
                    aW2[of] = *(const bf16x8*)&LDSU[W2B_OFF + pp * W2B_STR + swz(wo * 64 + of * 16 + lr, KC, kk * 64 + lg * 16)];
#pragma unroll
                for (int nf = 0; nf < 2; ++nf)
                    bH[nf] = *(const bf16x8*)&LDSU[HB_OFF + pp * HB_STR + swz(wm * 32 + nf * 16 + lr, KC, kk * 64 + lg * 16)];
#pragma unroll
                for (int of = 0; of < 4; ++of)
#pragma unroll
                    for (int nf = 0; nf < 2; ++nf)
                        acc2[of][nf] = __builtin_amdgcn_mfma_f32_16x16x32_bf16(aW2[of], bH[nf], acc2[of][nf], 0, 0, 0);
            }
        }

        // (5) G1(c): D1[h][m] = W1(c)[h,k] * XC[m,k]  [W1B[pc]; B=xcreg]
        f32x4 acc1[4] = {};
#pragma unroll
        for (int kk = 0; kk < 6; ++kk) {
            bf16x8 aW[4];
#pragma unroll
            for (int hf = 0; hf < 4; ++hf)
                aW[hf] = *(const bf16x8*)&LDSU[W1B_OFF + pc * W1B_STR + swz(hf * 16 + lr, DIN_, kk * 64 + lg * 16)];
#pragma unroll
            for (int hf = 0; hf < 4; ++hf)
                acc1[hf] = __builtin_amdgcn_mfma_f32_16x16x32_bf16(aW[hf], xcreg[kk], acc1[hf], 0, 0, 0);
        }
        // (6) epilogue: HB[pc][m][h] = relu(acc1+b1), 4 consecutive h -> b64
#pragma unroll
        for (int hf = 0; hf < 4; ++hf) {
            float4 b1f = *(const float4*)&b1[e * DH_ + c * KC + hf * 16 + lg * 4];
            float v0 = fmaxf(acc1[hf][0] + b1f.x, 0.f);
            float v1 = fmaxf(acc1[hf][1] + b1f.y, 0.f);
            float v2 = fmaxf(acc1[hf][2] + b1f.z, 0.f);
            float v3 = fmaxf(acc1[hf][3] + b1f.w, 0.f);
            uint2 hv;
            hv.x = f2bf_u(v0) | (f2bf_u(v1) << 16);
            hv.y = f2bf_u(v2) | (f2bf_u(v3) << 16);
            int m = w * 16 + lr;
            *(uint2*)&LDSU[HB_OFF + pc * HB_STR + swz(m, KC, hf * 32 + lg * 8)] = hv;
        }

        __syncthreads();   // the ONE barrier (drains DMA + LDS, flips parities)
    }

    // ---- drain: G2(15) at parity 1 ----
#pragma unroll
    for (int kk = 0; kk < 2; ++kk) {
        bf16x8 aW2[4], bH[2];
#pragma unroll
        for (int of = 0; of < 4; ++of)
            aW2[of] = *(const bf16x8*)&LDSU[W2B_OFF + W2B_STR + swz(wo * 64 + of * 16 + lr, KC, kk * 64 + lg * 16)];
#pragma unroll
        for (int nf = 0; nf < 2; ++nf)
            bH[nf] = *(const bf16x8*)&LDSU[HB_OFF + HB_STR + swz(wm * 32 + nf * 16 + lr, KC, kk * 64 + lg * 16)];
#pragma unroll
        for (int of = 0; of < 4; ++of)
#pragma unroll
            for (int nf = 0; nf < 2; ++nf)
                acc2[of][nf] = __builtin_amdgcn_mfma_f32_16x16x32_bf16(aW2[of], bH[nf], acc2[of][nf], 0, 0, 0);
    }

    // ---- out: y[m][o] = acc2[o][m] + b2[o]; 4 consecutive o -> dwordx4 ----
#pragma unroll
    for (int of = 0; of < 4; ++of) {
        float4 b2f = *(const float4*)&b2[e * DO_ + wo * 64 + of * 16 + lg * 4];
#pragma unroll
        for (int nf = 0; nf < 2; ++nf) {
            int m = wm * 32 + nf * 16 + lr;
            float4 val;
            val.x = acc2[of][nf][0] + b2f.x;
            val.y = acc2[of][nf][1] + b2f.y;
            val.z = acc2[of][nf][2] + b2f.z;
            val.w = acc2[of][nf][3] + b2f.w;
            *(float4*)&out[(size_t)(e * B_ + row0 + m) * DO_ + wo * 64 + of * 16 + lg * 4] = val;
        }
    }
}

extern "C" void kernel_launch(void* const* d_in, const int* in_sizes, int n_in,
                              void* d_out, int out_size, void* d_ws, size_t ws_size,
                              hipStream_t stream) {
    const float* x    = (const float*)d_in[0];
    const float* cond = (const float*)d_in[1];
    const float* W1   = (const float*)d_in[2];
    const float* b1   = (const float*)d_in[3];
    const float* W2   = (const float*)d_in[4];
    const float* b2   = (const float*)d_in[5];
    float* out = (float*)d_out;

    dim3 grid(E_ * (B_ / BM));   // 256 blocks = 1 per CU
    dim3 block(NT);

    const bool usews = (ws_size >= WS_BYTES) && (d_ws != nullptr);
    if (usews) {
        convert_w<<<2560, 256, 0, stream>>>((const float4*)W1, (const float4*)W2,
                                            (uint2*)d_ws);
        moe_fused_kernel<true><<<grid, block, 0, stream>>>(
            x, cond, W1, b1, W2, b2, (const uint2*)d_ws, out);
    } else {
        moe_fused_kernel<false><<<grid, block, 0, stream>>>(
            x, cond, W1, b1, W2, b2, (const uint2*)nullptr, out);
    }
}